// Round 12
// baseline (275.760 us; speedup 1.0000x reference)
//
#include <hip/hip_runtime.h>

typedef unsigned short u16;
typedef unsigned int u32;
typedef __bf16 bf16x8 __attribute__((ext_vector_type(8)));
typedef float f32x16 __attribute__((ext_vector_type(16)));
typedef float f32x4 __attribute__((ext_vector_type(4)));
typedef unsigned short ushort8 __attribute__((ext_vector_type(8)));
typedef unsigned int uint4v __attribute__((ext_vector_type(4)));

// 1/sqrt(65) * log2(e) folded into Q at projection time (exp2 direct in attn)
#define QSCALE2 0.17894429680154087f

__device__ __forceinline__ u16 f2bf(float f) {
  unsigned u = __float_as_uint(f);
  u = (u + 0x7fffu + ((u >> 16) & 1u)) >> 16;
  return (u16)u;
}

__device__ __forceinline__ f32x16 zero16() {
  f32x16 z;
#pragma unroll
  for (int i = 0; i < 16; ++i) z[i] = 0.0f;
  return z;
}

// async global->LDS, 16B per lane; lds dest = base + lane*16 (linear)
__device__ __forceinline__ void gload_lds16(const u16* g, u16* l) {
  __builtin_amdgcn_global_load_lds(
      (const __attribute__((address_space(1))) void*)g,
      (__attribute__((address_space(3))) void*)l, 16, 0, 0);
}

__device__ __forceinline__ u32 cvtpk_bf16(float lo, float hi) {
  u32 r;
  asm("v_cvt_pk_bf16_f32 %0, %1, %2" : "=v"(r) : "v"(lo), "v"(hi));
  return r;
}

// ---- convert inp (f32) -> xb (bf16) ----
__global__ __launch_bounds__(256) void cvt_x_kernel(const float4* __restrict__ in,
                                                    ushort4* __restrict__ out) {
  int i = blockIdx.x * 256 + threadIdx.x;
  float4 v = in[i];
  ushort4 o;
  o.x = f2bf(v.x); o.y = f2bf(v.y); o.z = f2bf(v.z); o.w = f2bf(v.w);
  out[i] = o;
}

// ---- convert weights -> wtt bf16 [wsel][544][512]; wtt[w][j][k] = w[j][k+4] ----
__global__ __launch_bounds__(256) void cvt_w_kernel(const float* __restrict__ wq,
                                                    const float* __restrict__ wk,
                                                    const float* __restrict__ wv,
                                                    u16* __restrict__ wtt) {
  int id = blockIdx.x * 256 + threadIdx.x;
  int wsel = id / (544 * 512);
  int rem = id - wsel * (544 * 512);
  int j = rem >> 9, k = rem & 511;
  const float* wp = (wsel == 0) ? wq : (wsel == 1) ? wk : wv;
  float v = (j < 520) ? wp[j * 520 + k + 4] : 0.0f;
  wtt[id] = f2bf(v);
}

__global__ __launch_bounds__(256) void zero_kernel(uint4* __restrict__ p, int n) {
  int i = blockIdx.x * 256 + threadIdx.x;
  uint4 z = make_uint4(0u, 0u, 0u, 0u);
  for (; i < n; i += gridDim.x * 256) p[i] = z;
}

// ---- projection GEMM ----
__global__ __launch_bounds__(256) void proj_kernel(const u16* __restrict__ xb,
                                                   const u16* __restrict__ wtt,
                                                   u16* __restrict__ qb,
                                                   u16* __restrict__ kpl,
                                                   u16* __restrict__ vb) {
  int tid = threadIdx.x;
  int w = tid >> 6, l = tid & 63, lr = l & 31, lh = l >> 5;
  int m0 = blockIdx.y * 128 + w * 32;
  int g = blockIdx.x;

  const u16* ap = xb + (size_t)(m0 + lr) * 512 + lh * 8;

  f32x16 acc[4];
  const u16* bp[4];
  bool valid[4];
#pragma unroll
  for (int i = 0; i < 4; ++i) {
    int nt = g * 4 + i;
    valid[i] = (nt < 51);
    int ntc = valid[i] ? nt : 50;
    bp[i] = wtt + ((size_t)((ntc / 17) * 544 + (ntc % 17) * 32) + lr) * 512 + lh * 8;
    acc[i] = zero16();
  }

#pragma unroll 4
  for (int s = 0; s < 32; ++s) {
    bf16x8 a = *reinterpret_cast<const bf16x8*>(ap + s * 16);
#pragma unroll
    for (int i = 0; i < 4; ++i) {
      if (valid[i]) {
        bf16x8 b = *reinterpret_cast<const bf16x8*>(bp[i] + s * 16);
        acc[i] = __builtin_amdgcn_mfma_f32_32x32x16_bf16(a, b, acc[i], 0, 0, 0);
      }
    }
  }

#pragma unroll
  for (int i = 0; i < 4; ++i) {
    int nt = g * 4 + i;
    if (nt < 51) {
      int wsel = nt / 17;
      int j = (nt % 17) * 32 + lr;
      if (j < 520) {
        int h = j / 65, dh = j - h * 65;
#pragma unroll
        for (int r = 0; r < 16; ++r) {
          int m = m0 + (r & 3) + 8 * (r >> 2) + 4 * lh;
          int bb = m >> 11, lrow = m & 2047;
          int bh = bb * 8 + h;
          if (wsel == 0) {
            qb[((size_t)bh * 2048 + lrow) * 80 + dh] = f2bf(acc[i][r] * QSCALE2);
          } else if (wsel == 1) {
            kpl[(((size_t)bh * 10 + (dh >> 3)) * 2048 + lrow) * 8 + (dh & 7)] = f2bf(acc[i][r]);
          } else {
            vb[((size_t)bh * 2048 + lrow) * 80 + dh] = f2bf(acc[i][r]);
          }
        }
      }
    }
  }
}

// ---- V repack: vb (bh, key, 80) -> vpl[((bh*256 + key/8)*80 + d)*8 + key%8] ----
__global__ __launch_bounds__(256) void repack_v_kernel(const u16* __restrict__ vb,
                                                       u16* __restrict__ vpl) {
  __shared__ u16 lds[256 * 88];
  int bh = blockIdx.y;
  int key0 = blockIdx.x * 256;
  int t = threadIdx.x;

  const u16* src = vb + ((size_t)bh * 2048 + key0) * 80;
#pragma unroll
  for (int i = 0; i < 10; ++i) {
    int f16 = i * 256 + t;
    int row = f16 / 10, col = f16 % 10;
    ushort8 v = *reinterpret_cast<const ushort8*>(src + f16 * 8);
    *reinterpret_cast<ushort8*>(&lds[row * 88 + col * 8]) = v;
  }
  __syncthreads();

#pragma unroll
  for (int j = 0; j < 10; ++j) {
    int slot = j * 256 + t;
    int kc = slot / 80, d = slot - kc * 80;
    ushort8 v;
#pragma unroll
    for (int e = 0; e < 8; ++e) v[e] = lds[(kc * 8 + e) * 88 + d];
    *reinterpret_cast<ushort8*>(
        &vpl[(((size_t)bh * 256 + (key0 >> 3) + kc) * 80 + d) * 8]) = v;
  }
}

// ---- pass 1: row sums of exp2(S), swapped QK (lane = q-row), staged K ----
// grid 512, block 256 (4 waves x 32 rows). Writes sums[bh][qrow] f32.
__global__ __launch_bounds__(256, 2) void pass1_kernel(const u16* __restrict__ qb,
                                                       const u16* __restrict__ kpl,
                                                       float* __restrict__ sums) {
  __shared__ u16 kbuf[2][10240];   // 2 x 20 KB: K tile of 128 keys

  int b = blockIdx.x;
  int bh = (b & 7) + 8 * (b >> 7);
  int qblk = (b >> 3) & 15;
  int tid = threadIdx.x;
  int w = tid >> 6, l = tid & 63, lr = l & 31, lh = l >> 5;
  int q0 = qblk * 128 + w * 32;

  const u16* kbh = kpl + (size_t)bh * 163840;

  // Q fragments: B-operand, lane lr <-> q-row q0+lr, k = 16s+8lh+e
  const u16* qptr = qb + ((size_t)bh * 2048 + q0 + lr) * 80 + lh * 8;
  bf16x8 qf[5];
#pragma unroll
  for (int s = 0; s < 5; ++s) qf[s] = *reinterpret_cast<const bf16x8*>(qptr + s * 16);

  float rsum = 0.0f;

#define STAGE_K128(kt, bufi)                                                  \
  {                                                                           \
    _Pragma("unroll")                                                         \
    for (int i = 0; i < 5; ++i) {                                             \
      int idx = w + i * 4;                                                    \
      int c = idx >> 1, half = idx & 1;                                       \
      gload_lds16(kbh + (size_t)c * 16384 + (kt) * 1024 + half * 512 + l * 8, \
                  &kbuf[bufi][idx * 512]);                                    \
    }                                                                         \
  }

  STAGE_K128(0, 0);
  __syncthreads();
  int buf = 0;
  for (int t = 0; t < 16; ++t) {
    if (t < 15) STAGE_K128(t + 1, buf ^ 1);
#pragma unroll
    for (int sub = 0; sub < 4; ++sub) {
      f32x16 acc = zero16();
#pragma unroll
      for (int s = 0; s < 5; ++s) {
        bf16x8 bk = *reinterpret_cast<const bf16x8*>(
            &kbuf[buf][((2 * s + lh) * 128 + sub * 32 + lr) * 8]);
        acc = __builtin_amdgcn_mfma_f32_32x32x16_bf16(bk, qf[s], acc, 0, 0, 0);
      }
#pragma unroll
      for (int r2 = 0; r2 < 16; ++r2) rsum += __builtin_amdgcn_exp2f(acc[r2]);
    }
    __syncthreads();
    buf ^= 1;
  }

  // lane's rsum covers its lh-half of keys for q-row q0+lr; combine halves
  float tot = rsum + __shfl_xor(rsum, 32);
  if (l < 32) sums[(size_t)bh * 2048 + q0 + l] = tot;
}

// ---- pass 2: recompute S (swapped), write attn via dwordx4 from regs, PV ----
// grid 512, block 256 (4 waves x 32 rows). 3-buffer KV staging, vmcnt(28).
__global__ __launch_bounds__(256) void pass2_kernel(const u16* __restrict__ qb,
                                                    const u16* __restrict__ kpl,
                                                    const u16* __restrict__ vpl,
                                                    const float* __restrict__ sums,
                                                    float* __restrict__ out,
                                                    float* __restrict__ attn) {
  __shared__ u16 kvbuf[3][10368];   // 3 x 20.25 KB (pad covers d>=80 frag reads)

  int b = blockIdx.x;
  int bh = (b & 7) + 8 * (b >> 7);
  int qblk = (b >> 3) & 15;
  int tid = threadIdx.x;
  int w = tid >> 6, l = tid & 63, lr = l & 31, lh = l >> 5;
  int q0 = qblk * 128 + w * 32;
  int phase = (b * 11) & 31;

  const u16* kbh = kpl + (size_t)bh * 163840;
  const u16* vbh = vpl + (size_t)bh * 163840;

  const u16* qptr = qb + ((size_t)bh * 2048 + q0 + lr) * 80 + lh * 8;
  bf16x8 qf[5];
#pragma unroll
  for (int s = 0; s < 5; ++s) qf[s] = *reinterpret_cast<const bf16x8*>(qptr + s * 16);

  float inv = 1.0f / sums[(size_t)bh * 2048 + q0 + lr];

#define STAGE_KV64(t64, bufi)                                                 \
  {                                                                           \
    _Pragma("unroll")                                                         \
    for (int i = 0; i < 5; ++i) {                                             \
      int idx = w + i * 4;                                                    \
      const u16* src = (idx < 10)                                             \
          ? kbh + (size_t)idx * 16384 + (t64) * 512 + l * 8                   \
          : vbh + (size_t)(t64) * 5120 + (idx - 10) * 512 + l * 8;            \
      gload_lds16(src, &kvbuf[bufi][idx * 512]);                              \
    }                                                                         \
  }

  f32x16 O[3];
#pragma unroll
  for (int n = 0; n < 3; ++n) O[n] = zero16();

  // per-lane attn row pointer (q-row = q0+lr)
  float* arow = attn + ((size_t)bh * 2048 + q0 + lr) * 2048;

  STAGE_KV64(phase, 0);
  STAGE_KV64((phase + 1) & 31, 1);
  __syncthreads();
  for (int t = 0; t < 32; ++t) {
    int tt = (t + phase) & 31;
    int buf = t % 3;
    if (t < 30) STAGE_KV64((tt + 2) & 31, (t + 2) % 3);
#pragma unroll
    for (int sub = 0; sub < 2; ++sub) {
      int key0 = tt * 64 + sub * 32;
      f32x16 acc = zero16();
#pragma unroll
      for (int s = 0; s < 5; ++s) {
        bf16x8 bk = *reinterpret_cast<const bf16x8*>(
            &kvbuf[buf][((2 * s + lh) * 64 + sub * 32 + lr) * 8]);
        acc = __builtin_amdgcn_mfma_f32_32x32x16_bf16(bk, qf[s], acc, 0, 0, 0);
      }
      // p[r] = P[q=lr][key = key0 + (r&3)+8*(r>>2)+4*lh]
      float p[16];
#pragma unroll
      for (int r2 = 0; r2 < 16; ++r2)
        p[r2] = __builtin_amdgcn_exp2f(acc[r2]) * inv;

      // ---- attn stores: 4x dwordx4 direct from regs (keys 8j+4lh..+3) ----
#pragma unroll
      for (int j = 0; j < 4; ++j) {
        f32x4 vv;
        vv[0] = p[4 * j]; vv[1] = p[4 * j + 1];
        vv[2] = p[4 * j + 2]; vv[3] = p[4 * j + 3];
        *reinterpret_cast<f32x4*>(&arow[key0 + 8 * j + 4 * lh]) = vv;
      }

      // ---- PV A-fragments in registers: cvt_pk + permlane32_swap (r9-validated) ----
      u32 u01 = cvtpk_bf16(p[0], p[1]),  u23 = cvtpk_bf16(p[2], p[3]);
      u32 v01 = cvtpk_bf16(p[4], p[5]),  v23 = cvtpk_bf16(p[6], p[7]);
      u32 x01 = cvtpk_bf16(p[8], p[9]),  x23 = cvtpk_bf16(p[10], p[11]);
      u32 y01 = cvtpk_bf16(p[12], p[13]), y23 = cvtpk_bf16(p[14], p[15]);
      asm("v_permlane32_swap_b32 %0, %1" : "+v"(u01), "+v"(v01));
      asm("v_permlane32_swap_b32 %0, %1" : "+v"(u23), "+v"(v23));
      asm("v_permlane32_swap_b32 %0, %1" : "+v"(x01), "+v"(y01));
      asm("v_permlane32_swap_b32 %0, %1" : "+v"(x23), "+v"(y23));
      uint4v pw0, pw1;
      pw0[0] = u01; pw0[1] = u23; pw0[2] = v01; pw0[3] = v23;  // keys 0..15
      pw1[0] = x01; pw1[1] = x23; pw1[2] = y01; pw1[3] = y23;  // keys 16..31
      bf16x8 pa0 = __builtin_bit_cast(bf16x8, pw0);
      bf16x8 pa1 = __builtin_bit_cast(bf16x8, pw1);

#pragma unroll
      for (int ks = 0; ks < 2; ++ks) {
        bf16x8 pa = ks ? pa1 : pa0;
#pragma unroll
        for (int n = 0; n < 3; ++n) {
          bf16x8 bv = *reinterpret_cast<const bf16x8*>(
              &kvbuf[buf][5120 + ((sub * 4 + 2 * ks + lh) * 80 + n * 32 + lr) * 8]);
          O[n] = __builtin_amdgcn_mfma_f32_32x32x16_bf16(pa, bv, O[n], 0, 0, 0);
        }
      }
    }
    // allow [S(t)=8 stores][L(t+2)=20 loads] to remain; retires L(t+1) + older
    asm volatile("s_waitcnt vmcnt(28)" ::: "memory");
    __builtin_amdgcn_s_barrier();
  }

  // ---- out write: C row = q-row-local (r2 decode), col = d = n*32+lr
  int bb = bh >> 3, h = bh & 7;
#pragma unroll
  for (int n = 0; n < 3; ++n) {
    int d = n * 32 + lr;
    int cc = h * 65 + d - 4;
    if (d < 65 && cc >= 0 && cc < 512) {
#pragma unroll
      for (int r2 = 0; r2 < 16; ++r2) {
        int row = (r2 & 3) + 8 * (r2 >> 2) + 4 * lh;
        out[((size_t)bb * 2048 + q0 + row) * 512 + cc] = O[n][r2];
      }
    }
  }
}

extern "C" void kernel_launch(void* const* d_in, const int* in_sizes, int n_in,
                              void* d_out, int out_size, void* d_ws, size_t ws_size,
                              hipStream_t stream) {
  (void)in_sizes; (void)n_in; (void)out_size; (void)ws_size;
  const float* inp = (const float*)d_in[0];
  const float* wq  = (const float*)d_in[1];
  const float* wk  = (const float*)d_in[2];
  const float* wv  = (const float*)d_in[3];

  char* ws = (char*)d_ws;
  u16* xb   = (u16*)(ws + 0);                        // 8,388,608
  u16* wtt  = (u16*)(ws + 8388608);                  // 1,671,168
  u16* qb   = (u16*)(ws + 10059776);                 // 10,485,760
  u16* kpl  = (u16*)(ws + 20545536);                 // 10,485,760 (planar K)
  u16* vb   = (u16*)(ws + 31031296);                 // 10,485,760
  u16* vpl  = (u16*)(ws + 41517056);                 // 10,485,760 (planar V)
  float* sums = (float*)(ws + 52002816);             // 65536*4 = 262,144

  float* out  = (float*)d_out;
  float* attn = out + (size_t)4 * 2048 * 512;

  cvt_x_kernel<<<4096, 256, 0, stream>>>((const float4*)inp, (ushort4*)xb);
  cvt_w_kernel<<<3264, 256, 0, stream>>>(wq, wk, wv, wtt);
  // zero qb only: Q pads must be 0 (K/V pad garbage is annihilated by q-pad zeros
  // in QK and discarded rows in PV; 0xAA poison is finite bf16)
  zero_kernel<<<640, 256, 0, stream>>>((uint4*)qb, 655360);
  proj_kernel<<<dim3(13, 64), 256, 0, stream>>>(xb, wtt, qb, kpl, vb);
  pass1_kernel<<<512, 256, 0, stream>>>(qb, kpl, sums);
  repack_v_kernel<<<dim3(8, 32), 256, 0, stream>>>(vb, vpl);
  pass2_kernel<<<512, 256, 0, stream>>>(qb, kpl, vpl, sums, out, attn);
}